// Round 7
// baseline (274.447 us; speedup 1.0000x reference)
//
#include <hip/hip_runtime.h>

// Problem constants (fixed by the reference's setup_inputs).
#define BATCH 8
#define CH    16
#define HH    512
#define WW    512
#define HW    (HH * WW)     // 262144

#define TILW  32            // output tile width per block
#define TILH  64            // output tile height per block
#define RPAD  16            // halo radius staged in LDS
#define REGW  64            // staged region width  = TILW + 2*RPAD
#define REGH  96            // staged region height = TILH + 2*RPAD
#define NPX   4             // pixels per thread = 32*64 / 512
#define NTHR  512

// R7: explicit counted stores -- fix the vmcnt queue accounting.
//
// R6 post-mortem: VGPR=60 (res[16][4]=64 floats can't fit) + no scratch
// traffic proves the compiler SANK the output stores into the phase loop.
// The in-order vmcnt queue therefore contained 4 uncounted stores per
// phase at compiler-chosen positions, so WAITVM(3) -- which leaves only
// the 3 NEWEST ops outstanding -- was retiring S(g+2) as well (issued
// only ~1 phase earlier, ~900cy HBM-miss latency not yet covered) plus
// store acks. The "depth-3" pipeline ran at effective depth ~1.5 in R4
// AND R6. (R5 had correct accounting but bundled sched_barrier pinning +
// 3x fixup growth -- confounded, now untangled.)
//
// Fix: stores are explicit and PLACED: phase g =
//   { reads(g); st(g) x4; WAITVM(7); BAR; STAGE(g+3) x3 }
// Each inter-wait region holds exactly 7 VMEM ops (4 stores + 3 gll).
// vmcnt retirement is strictly in-order, so N=7 retires ALL of region
// g-1 -- including S(g+1), which the next gather needs -- regardless of
// how the compiler orders gll vs stores WITHIN a region, and never
// touches S(g+2)/S(g+3) (they stay in flight across the barrier).
// Stores being waited on are >=1 full phase old (L2 write acks long
// returned). Tail: wait(14)=4, phase 15 unwaited. No sched_barrier
// (R5's mistake), gather/fixup identical to R6 (no fixup growth).
//
// Geometry (R6-proven): tile 32x64 per 512-thread block, region 64x96,
// buf[3][96][64] fp32 = 72 KB -> 2 blocks/CU (16 waves/CU). Grid 1024 =
// 2 rounds of 512 resident blocks. XCD swizzle (bijective, 1024%8==0):
// each XCD owns one batch -> halo reuse intra-XCD L2 (FETCH 229->109MB).
//
// Staging: __builtin_amdgcn_global_load_lds width=16; 1 instr/wave = 1KB
// = 4 rows x 64 floats (wave-uniform LDS dest + lane*16; per-lane global
// source). 3 instrs/wave per plane. Source chunks 16B-aligned (x0r
// multiple of 16 floats), never straddle an image row; fully-out-of-image
// chunks offset-clamped -> finite garbage only in cells no clamped corner
// of a non-fixup pixel references (fixup pixels recomputed from global
// after; same thread stores both -> program order gives the final value).
//
// Kept: flow loads hoisted oldest in the vmcnt queue, fbmask +
// fixup-recompute, mask folded into weights on UNCLIPPED floor coords
// (bit-exact vs reference).

typedef __attribute__((address_space(1))) const void global_cvoid;
typedef __attribute__((address_space(3))) void lds_void;

__device__ __forceinline__ void gll16(const float* g, float* l) {
    __builtin_amdgcn_global_load_lds((global_cvoid*)g, (lds_void*)l, 16, 0, 0);
}

#define WAITVM(n) asm volatile("s_waitcnt vmcnt(" #n ")" ::: "memory")
#define BAR()     __builtin_amdgcn_s_barrier()

// Stage channel plane g into buffer nb: 3 gll16 per wave (quads k*8+wv).
#define STAGE(g, nb) do {                                               \
    const float* pc_ = img + ib + (size_t)(g) * HW;                     \
    _Pragma("unroll")                                                   \
    for (int k_ = 0; k_ < 3; ++k_) {                                    \
        gll16(pc_ + goff[k_], &buf[nb][(k_ * 8 + wv) * 4][0]);          \
    }                                                                   \
} while (0)

// Gather channel g from buffer cb and store it (4 counted stores).
#define GATHERST(g, cb) do {                                            \
    const float* pl_ = &buf[cb][0][0];                                  \
    float* o0_ = out + ib + (size_t)(g) * HW;                           \
    _Pragma("unroll")                                                   \
    for (int p_ = 0; p_ < NPX; ++p_) {                                  \
        const int l_   = lidx[p_];                                      \
        const int dx_  = dxv[p_];                                       \
        const int dyo_ = dyov[p_];                                      \
        const float v00 = pl_[l_];                                      \
        const float v01 = pl_[l_ + dx_];                                \
        const float v10 = pl_[l_ + dyo_];                               \
        const float v11 = pl_[l_ + dx_ + dyo_];                         \
        o0_[obase[p_]] = w00[p_]*v00 + w01[p_]*v01                      \
                       + w10[p_]*v10 + w11[p_]*v11;                     \
    }                                                                   \
} while (0)

// Full phase: gather+store g, retire exactly region g-1 (incl S(g+1)),
// barrier, refill the just-consumed buffer with plane g+3.
#define PHASE(g) do {                                                   \
    GATHERST(g, (g) % 3);                                               \
    WAITVM(7);                                                          \
    BAR();                                                              \
    STAGE((g) + 3, (g) % 3);                                            \
} while (0)

__global__ __launch_bounds__(NTHR, 4) void warp_cst(
    const float* __restrict__ img,
    const float* __restrict__ flo,
    float* __restrict__ out)
{
    __shared__ float buf[3][REGH][REGW];   // 72 KB -> 2 blocks/CU

    const int t   = threadIdx.x;
    const int bid = blockIdx.x;           // 0..1023
    const int tile = (bid & 7) * 128 + (bid >> 3);   // XCD = one batch
    const int b    = tile >> 7;           // 128 tiles per batch
    const int ti   = tile & 127;
    const int ty   = ti >> 4;             // 0..7
    const int tx   = ti & 15;             // 0..15
    const int xb   = tx * TILW;
    const int yb   = ty * TILH;
    const int x0r  = xb - RPAD;           // region origin (may be negative)
    const int y0r  = yb - RPAD;

    // ---- staging geometry (channel-invariant) ----
    const int lane = t & 63;
    const int wv   = t >> 6;              // wave id 0..7 (wave-uniform)
    const int sub  = lane >> 4;           // row-within-quad 0..3
    const int xch  = x0r + (lane & 15) * 4;  // this lane's 4-float x chunk
    const size_t ib = (size_t)b * CH * HW;

    int goff[3];                          // per-lane staged global offsets
#pragma unroll
    for (int k = 0; k < 3; ++k) {
        const int q  = k * 8 + wv;        // quad 0..23
        const int ry = q * 4 + sub;       // this lane's region row 0..95
        const int gy = min(max(y0r + ry, 0), HH - 1);
        goff[k] = min(max(gy * WW + xch, 0), HW - 4);
    }

    // ---- flow loads FIRST (oldest in the in-order vmcnt queue) ----
    const float* fbp = flo + (size_t)b * 2 * HW;
    float fxv[NPX], fyv[NPX];
#pragma unroll
    for (int p = 0; p < NPX; ++p) {
        const int pix = p * NTHR + t;
        const int hw  = (yb + (pix >> 5)) * WW + xb + (pix & 31);
        fxv[p] = fbp[hw];                 // coalesced
        fyv[p] = fbp[HW + hw];
    }
    asm volatile("" ::: "memory");        // pin: flow loads precede all gll

    // ---- pre-issue staging for groups 0..2 (all three buffers) ----
    STAGE(0, 0);
    STAGE(1, 1);
    STAGE(2, 2);

    // ---- per-pixel precompute (register-only; hides staging latency) ----
    // Compiler's dependent wait for fxv/fyv drains flow only (oldest).
    float w00[NPX], w01[NPX], w10[NPX], w11[NPX];
    int   lidx[NPX], dxv[NPX], dyov[NPX], obase[NPX];
    int   fbmask = 0;

#pragma unroll
    for (int p = 0; p < NPX; ++p) {
        const int pix = p * NTHR + t;     // 0..2047 within tile
        const int row = pix >> 5;         // 0..63
        const int col = pix & 31;
        const int h   = yb + row;
        const int w   = xb + col;
        obase[p] = h * WW + w;

        const float gx = (float)w + fxv[p];
        const float gy = (float)h + fyv[p];

        const float x0f = floorf(gx), y0f = floorf(gy);
        const float wx1 = gx - x0f, wx0 = 1.0f - wx1;
        const float wy1 = gy - y0f, wy0 = 1.0f - wy1;

        const bool vx0 = (x0f >= 0.0f)        && (x0f <= (float)(WW - 1));
        const bool vx1 = (x0f + 1.0f >= 0.0f) && (x0f + 1.0f <= (float)(WW - 1));
        const bool vy0 = (y0f >= 0.0f)        && (y0f <= (float)(HH - 1));
        const bool vy1 = (y0f + 1.0f >= 0.0f) && (y0f + 1.0f <= (float)(HH - 1));

        float a00 = wx0 * wy0 * ((vx0 && vy0) ? 1.0f : 0.0f);
        float a01 = wx1 * wy0 * ((vx1 && vy0) ? 1.0f : 0.0f);
        float a10 = wx0 * wy1 * ((vx0 && vy1) ? 1.0f : 0.0f);
        float a11 = wx1 * wy1 * ((vx1 && vy1) ? 1.0f : 0.0f);

        const float msum = a00 + a01 + a10 + a11;
        const float mask = (msum < 0.9999f) ? 0.0f : 1.0f;
        w00[p] = a00 * mask; w01[p] = a01 * mask;
        w10[p] = a10 * mask; w11[p] = a11 * mask;

        const int x0 = min(max((int)x0f, 0), WW - 1);
        const int x1 = min(max((int)x0f + 1, 0), WW - 1);
        const int y0 = min(max((int)y0f, 0), HH - 1);
        const int y1 = min(max((int)y0f + 1, 0), HH - 1);

        const int dx = x1 - x0;           // 0 or 1
        const int dy = y1 - y0;
        dxv[p]  = dx;
        dyov[p] = dy * REGW;

        const int xl = x0 - x0r;          // region-local (may be out of range)
        const int yl = y0 - y0r;
        if (!((xl >= 0) && (xl + dx <= REGW - 1) &&
              (yl >= 0) && (yl + dy <= REGH - 1)))
            fbmask |= (1 << p);
        // Clamp: no-op for in-region pixels, safe-finite for fixup pixels.
        lidx[p] = min(max(yl, 0), REGH - 2) * REGW + min(max(xl, 0), REGW - 2);
    }

    // ---- prologue handoff: retire S0 only (S1,S2 stay in flight) ----
    // Queue here: [S0,S1,S2] = 9 (flow drained by the precompute's use).
    WAITVM(6);
    BAR();

    // ---- 16 phases; every inter-wait region = 7 VMEM ops (4 st + 3 gll).
    // N=7 retires exactly the previous region (incl S(g+1)); S(g+2)/S(g+3)
    // stay in flight across the barrier. Never a full mid-loop drain.
    PHASE(0);   PHASE(1);   PHASE(2);   PHASE(3);
    PHASE(4);   PHASE(5);   PHASE(6);   PHASE(7);
    PHASE(8);   PHASE(9);   PHASE(10);  PHASE(11);
    PHASE(12);
    // phase 13: region = [S15, reads13, st13]; wait(7) retires region 12
    // (incl S14). No STAGE(16).
    GATHERST(13, 1);  WAITVM(7);  BAR();
    // phase 14: region = [reads14, st14] (4 ops); wait(4) retires region 13
    // (incl S15).
    GATHERST(14, 2);  WAITVM(4);  BAR();
    // phase 15: nothing left to wait for.
    GATHERST(15, 0);

    // ---- fixup: redo fallback pixels from global (all 16 channels) ----
    // Rare path (~2% of pixels). Exact reference math; L2/L3-warm loads.
    // Same-thread rewrite of the same addresses -> program order wins.
    if (fbmask) {
#pragma unroll
        for (int p = 0; p < NPX; ++p) {
            if (!(fbmask & (1 << p))) continue;
            const int pix = p * NTHR + t;
            const int row = pix >> 5;
            const int col = pix & 31;
            const int h   = yb + row;
            const int w   = xb + col;
            const int hw  = h * WW + w;

            const float gx = (float)w + fxv[p];
            const float gy = (float)h + fyv[p];

            const float x0f = floorf(gx), y0f = floorf(gy);
            const float wx1 = gx - x0f, wx0 = 1.0f - wx1;
            const float wy1 = gy - y0f, wy0 = 1.0f - wy1;

            const bool vx0 = (x0f >= 0.0f)        && (x0f <= (float)(WW - 1));
            const bool vx1 = (x0f + 1.0f >= 0.0f) && (x0f + 1.0f <= (float)(WW - 1));
            const bool vy0 = (y0f >= 0.0f)        && (y0f <= (float)(HH - 1));
            const bool vy1 = (y0f + 1.0f >= 0.0f) && (y0f + 1.0f <= (float)(HH - 1));

            float a00 = wx0 * wy0 * ((vx0 && vy0) ? 1.0f : 0.0f);
            float a01 = wx1 * wy0 * ((vx1 && vy0) ? 1.0f : 0.0f);
            float a10 = wx0 * wy1 * ((vx0 && vy1) ? 1.0f : 0.0f);
            float a11 = wx1 * wy1 * ((vx1 && vy1) ? 1.0f : 0.0f);

            const float msum = a00 + a01 + a10 + a11;
            const float mask = (msum < 0.9999f) ? 0.0f : 1.0f;
            a00 *= mask; a01 *= mask; a10 *= mask; a11 *= mask;

            const int x0 = min(max((int)x0f, 0), WW - 1);
            const int x1 = min(max((int)x0f + 1, 0), WW - 1);
            const int y0 = min(max((int)y0f, 0), HH - 1);
            const int y1 = min(max((int)y0f + 1, 0), HH - 1);

            const int gA  = y0 * WW + x0;
            const int dx  = x1 - x0;
            const int dyo = (y1 - y0) * WW;

            const float* ic = img + ib;
            float*       oc = out + ib + hw;
            for (int c = 0; c < CH; ++c) {
                const float* pc = ic + (size_t)c * HW;
                const float v = a00 * pc[gA]
                              + a01 * pc[gA + dx]
                              + a10 * pc[gA + dyo]
                              + a11 * pc[gA + dx + dyo];
                oc[(size_t)c * HW] = v;
            }
        }
    }
}

extern "C" void kernel_launch(void* const* d_in, const int* in_sizes, int n_in,
                              void* d_out, int out_size, void* d_ws, size_t ws_size,
                              hipStream_t stream) {
    const float* img = (const float*)d_in[0];  // [8,16,512,512] fp32
    const float* flo = (const float*)d_in[1];  // [8,2,512,512] fp32
    float* out = (float*)d_out;                // [8,16,512,512] fp32

    const int blocks = BATCH * (WW / TILW) * (HH / TILH);  // 1024
    warp_cst<<<blocks, NTHR, 0, stream>>>(img, flo, out);
}